// Round 7
// baseline (297.316 us; speedup 1.0000x reference)
//
#include <hip/hip_runtime.h>
#include <hip/hip_bf16.h>
#include <cmath>

// Problem constants
#define B_   8
#define N_   4096
#define DIN1 64
#define DHID 128
#define DOUT2 64
#define MAXDEG 256

// ---------------------------------------------------------------------------
// Kernel 1: adjacency -> fixed-stride neighbor lists (float4 scan).
// ---------------------------------------------------------------------------
__global__ __launch_bounds__(256) void k_build_csr(
    const float* __restrict__ graph, int* __restrict__ cnt, int* __restrict__ idx)
{
    const int n = blockIdx.x;
    __shared__ int lcnt;
    if (threadIdx.x == 0) lcnt = 0;
    __syncthreads();
    const float4* row4 = (const float4*)(graph + (size_t)n * N_);
    int* myidx = idx + (size_t)n * MAXDEG;
    for (int m4 = threadIdx.x; m4 < N_ / 4; m4 += 256) {
        float4 g = row4[m4];
        if (g.x != 0.0f) { int p = atomicAdd(&lcnt, 1); if (p < MAXDEG) myidx[p] = 4 * m4; }
        if (g.y != 0.0f) { int p = atomicAdd(&lcnt, 1); if (p < MAXDEG) myidx[p] = 4 * m4 + 1; }
        if (g.z != 0.0f) { int p = atomicAdd(&lcnt, 1); if (p < MAXDEG) myidx[p] = 4 * m4 + 2; }
        if (g.w != 0.0f) { int p = atomicAdd(&lcnt, 1); if (p < MAXDEG) myidx[p] = 4 * m4 + 3; }
    }
    __syncthreads();
    if (threadIdx.x == 0) cnt[n] = (lcnt < MAXDEG) ? lcnt : MAXDEG;
}

// ---------------------------------------------------------------------------
// Kernel 2: register-tiled linear. out[r,k] = sum_d x[r,d]*W[k,d].
// ---------------------------------------------------------------------------
template <int DIN, int DOUT>
__global__ __launch_bounds__(256) void k_linear(
    const float* __restrict__ x, const float* __restrict__ W,
    float* __restrict__ out)
{
    constexpr int CG = DOUT / 4;
    constexpr int RG = 256 / CG;
    constexpr int TR = 32 / RG;

    __shared__ float sWt[DIN][DOUT + 4];

    const int t = threadIdx.x;
    const float4* W4 = (const float4*)W;
    for (int i = t; i < DOUT * (DIN / 4); i += 256) {
        int kk = i / (DIN / 4);
        int d4 = i % (DIN / 4);
        float4 w = W4[i];
        sWt[4 * d4 + 0][kk] = w.x;
        sWt[4 * d4 + 1][kk] = w.y;
        sWt[4 * d4 + 2][kk] = w.z;
        sWt[4 * d4 + 3][kk] = w.w;
    }
    __syncthreads();

    const int rg = t / CG;
    const int c  = t % CG;
    const int base = blockIdx.x * 32;
    const float4* x4 = (const float4*)x;

    float acc[TR][4];
#pragma unroll
    for (int i = 0; i < TR; ++i)
#pragma unroll
        for (int j = 0; j < 4; ++j) acc[i][j] = 0.0f;

    for (int d4 = 0; d4 < DIN / 4; ++d4) {
        float4 xf[TR];
#pragma unroll
        for (int i = 0; i < TR; ++i)
            xf[i] = x4[(size_t)(base + rg * TR + i) * (DIN / 4) + d4];
        float4 wf[4];
#pragma unroll
        for (int dd = 0; dd < 4; ++dd)
            wf[dd] = *(const float4*)&sWt[4 * d4 + dd][4 * c];
#pragma unroll
        for (int i = 0; i < TR; ++i) {
            acc[i][0] += xf[i].x * wf[0].x + xf[i].y * wf[1].x + xf[i].z * wf[2].x + xf[i].w * wf[3].x;
            acc[i][1] += xf[i].x * wf[0].y + xf[i].y * wf[1].y + xf[i].z * wf[2].y + xf[i].w * wf[3].y;
            acc[i][2] += xf[i].x * wf[0].z + xf[i].y * wf[1].z + xf[i].z * wf[2].z + xf[i].w * wf[3].z;
            acc[i][3] += xf[i].x * wf[0].w + xf[i].y * wf[1].w + xf[i].z * wf[2].w + xf[i].w * wf[3].w;
        }
    }

#pragma unroll
    for (int i = 0; i < TR; ++i) {
        float4 o = {acc[i][0], acc[i][1], acc[i][2], acc[i][3]};
        ((float4*)out)[(size_t)(base + rg * TR + i) * CG + c] = o;
    }
}

// ---------------------------------------------------------------------------
// Kernel 3: online-softmax sparse masked attention. One query per wave;
// 4 groups of 16 lanes stream disjoint neighbor subsets (each neighbor row
// read from L2 exactly once). BRANCHLESS flash update (cndmask only, no
// divergent rescale path, exact -inf/masked handling). Depth-2 prefetch via
// 3 rotating buffers + unroll-3 (no register copies): ~2 iterations of L2
// latency in flight per wave. Zero __syncthreads (wave-private LDS).
// Exact torch masked_fill(s==0) semantics; all-masked uniform-softmax
// fallback = in-kernel rare path (column mean of h[b]; dead in practice).
// ---------------------------------------------------------------------------
template <int D, bool RELU>
__global__ __launch_bounds__(256) void k_attn(
    const float* __restrict__ h, const int* __restrict__ cnt,
    const int* __restrict__ idx, const float* __restrict__ bias,
    float* __restrict__ out)
{
    constexpr int V  = D / 4;    // float4s per row (32 or 16)
    constexpr int NF = V / 16;   // float4s per lane (2 or 1)

    const int bid  = blockIdx.x;
    const int b    = bid & 7;                    // batch -> XCD pinning
    const int wave = threadIdx.x >> 6;
    const int lane = threadIdx.x & 63;
    const int n    = (bid >> 3) * 4 + wave;      // one query per wave
    const int grp  = lane >> 4;                  // 4 neighbor streams
    const int gl   = lane & 15;

    __shared__ int s_nbr[4][MAXDEG];             // wave-private -> no barrier

    const int k = cnt[n];
    for (int j = lane; j < k; j += 64)
        s_nbr[wave][j] = idx[(size_t)n * MAXDEG + j];

    const float4* __restrict__ hb4 = (const float4*)(h + (size_t)b * N_ * D);
    float4 qf[NF];
#pragma unroll
    for (int i = 0; i < NF; ++i) qf[i] = hb4[(size_t)n * V + gl + 16 * i];

    float m = -INFINITY, s = 0.0f;
    float4 acc[NF];
#pragma unroll
    for (int i = 0; i < NF; ++i) acc[i] = {0.0f, 0.0f, 0.0f, 0.0f};

    // branchless flash update (handles m=-inf and masked p==0 exactly)
    auto process = [&](const float4 (&cur)[NF]) {
        float p = 0.0f;
#pragma unroll
        for (int i = 0; i < NF; ++i)
            p += qf[i].x * cur[i].x + qf[i].y * cur[i].y
               + qf[i].z * cur[i].z + qf[i].w * cur[i].w;
        p += __shfl_xor(p, 8, 64);
        p += __shfl_xor(p, 4, 64);
        p += __shfl_xor(p, 2, 64);
        p += __shfl_xor(p, 1, 64);
        const bool valid = (p != 0.0f);           // dot==0 => masked (torch)
        const float pm   = valid ? p : m;
        const float newm = fmaxf(m, pm);
        const float f = (m == newm) ? 1.0f : __expf(m - newm);
        const float e = valid ? __expf(p - newm) : 0.0f;
        s = s * f + e;
#pragma unroll
        for (int i = 0; i < NF; ++i) {
            acc[i].x = acc[i].x * f + e * cur[i].x;
            acc[i].y = acc[i].y * f + e * cur[i].y;
            acc[i].z = acc[i].z * f + e * cur[i].z;
            acc[i].w = acc[i].w * f + e * cur[i].w;
        }
        m = newm;
    };

    auto loadrow = [&](float4 (&r)[NF], int j) {
        const float4* hm = hb4 + (size_t)s_nbr[wave][j] * V;
#pragma unroll
        for (int i = 0; i < NF; ++i) r[i] = hm[gl + 16 * i];
    };

    // depth-2 software pipeline: 3 rotating buffers, unroll-3, no reg copies
    float4 r0[NF], r1[NF], r2[NF];
    {
        int j = grp;
        if (j     < k) loadrow(r0, j);
        if (j + 4 < k) loadrow(r1, j + 4);
        while (true) {
            if (j >= k) break;
            if (j + 8 < k) loadrow(r2, j + 8);
            process(r0);
            j += 4;
            if (j >= k) break;
            if (j + 8 < k) loadrow(r0, j + 8);
            process(r1);
            j += 4;
            if (j >= k) break;
            if (j + 8 < k) loadrow(r1, j + 8);
            process(r2);
            j += 4;
        }
    }

    // merge the 4 group states (xor 16, 32); all 64 lanes converge
#pragma unroll
    for (int mask = 16; mask <= 32; mask <<= 1) {
        const float m2 = __shfl_xor(m, mask, 64);
        const float s2 = __shfl_xor(s, mask, 64);
        float4 a2[NF];
#pragma unroll
        for (int i = 0; i < NF; ++i) {
            a2[i].x = __shfl_xor(acc[i].x, mask, 64);
            a2[i].y = __shfl_xor(acc[i].y, mask, 64);
            a2[i].z = __shfl_xor(acc[i].z, mask, 64);
            a2[i].w = __shfl_xor(acc[i].w, mask, 64);
        }
        const float mm = fmaxf(m, m2);
        const float f1 = (m  == mm) ? 1.0f : __expf(m  - mm);  // -inf guard
        const float f2 = (m2 == mm) ? 1.0f : __expf(m2 - mm);
        s = s * f1 + s2 * f2;
#pragma unroll
        for (int i = 0; i < NF; ++i) {
            acc[i].x = acc[i].x * f1 + a2[i].x * f2;
            acc[i].y = acc[i].y * f1 + a2[i].y * f2;
            acc[i].z = acc[i].z * f1 + a2[i].z * f2;
            acc[i].w = acc[i].w * f1 + a2[i].w * f2;
        }
        m = mm;
    }

    if (s > 0.0f) {
        // normal epilogue: group 0 (lanes 0..15) writes the row
        if (grp == 0) {
            const float4* bias4 = (const float4*)bias;
            const float inv = 1.0f / s;
#pragma unroll
            for (int i = 0; i < NF; ++i) {
                const float4 bi = bias4[gl + 16 * i];
                float4 o;
                o.x = acc[i].x * inv + bi.x;
                o.y = acc[i].y * inv + bi.y;
                o.z = acc[i].z * inv + bi.z;
                o.w = acc[i].w * inv + bi.w;
                if (RELU) {
                    o.x = fmaxf(o.x, 0.0f); o.y = fmaxf(o.y, 0.0f);
                    o.z = fmaxf(o.z, 0.0f); o.w = fmaxf(o.w, 0.0f);
                }
                ((float4*)out)[((size_t)b * N_ + n) * V + gl + 16 * i] = o;
            }
        }
    } else {
        // RARE path (all scores masked): uniform softmax over all N rows ->
        // column mean of h[b]. Wave-uniform branch; never taken in practice
        // (self-score = ||h||^2 > 0 unless the whole h row is exactly zero).
        constexpr int RS = 64 / V;               // row streams (2 or 4)
        const int sl = lane % V;
        const int rs = lane / V;
        float4 a = {0.0f, 0.0f, 0.0f, 0.0f};
        for (int row = rs; row < N_; row += RS) {
            float4 v = hb4[(size_t)row * V + sl];
            a.x += v.x; a.y += v.y; a.z += v.z; a.w += v.w;
        }
#pragma unroll
        for (int mask = V; mask < 64; mask <<= 1) {
            a.x += __shfl_xor(a.x, mask, 64);
            a.y += __shfl_xor(a.y, mask, 64);
            a.z += __shfl_xor(a.z, mask, 64);
            a.w += __shfl_xor(a.w, mask, 64);
        }
        if (lane < V) {
            constexpr float invN = 1.0f / (float)N_;
            const float4 bi = ((const float4*)bias)[sl];
            float4 o;
            o.x = a.x * invN + bi.x;
            o.y = a.y * invN + bi.y;
            o.z = a.z * invN + bi.z;
            o.w = a.w * invN + bi.w;
            if (RELU) {
                o.x = fmaxf(o.x, 0.0f); o.y = fmaxf(o.y, 0.0f);
                o.z = fmaxf(o.z, 0.0f); o.w = fmaxf(o.w, 0.0f);
            }
            ((float4*)out)[((size_t)b * N_ + n) * V + sl] = o;
        }
    }
}

// ---------------------------------------------------------------------------
// Launch
// ---------------------------------------------------------------------------
extern "C" void kernel_launch(void* const* d_in, const int* in_sizes, int n_in,
                              void* d_out, int out_size, void* d_ws, size_t ws_size,
                              hipStream_t stream) {
    (void)in_sizes; (void)n_in; (void)out_size; (void)ws_size;

    const float* flow_x = (const float*)d_in[0];
    const float* graph  = (const float*)d_in[1];
    const float* W1     = (const float*)d_in[2];
    const float* b1     = (const float*)d_in[3];
    const float* W2     = (const float*)d_in[4];
    const float* b2     = (const float*)d_in[5];
    float* out = (float*)d_out;

    char* p = (char*)d_ws;
    auto carve = [&](size_t bytes) -> void* {
        void* r = (void*)p;
        p += (bytes + 255) & ~(size_t)255;
        return r;
    };
    int*   nbr_cnt = (int*)carve((size_t)N_ * sizeof(int));
    int*   nbr_idx = (int*)carve((size_t)N_ * MAXDEG * sizeof(int));
    float* h1      = (float*)carve((size_t)B_ * N_ * DHID * sizeof(float));
    float* x2      = (float*)carve((size_t)B_ * N_ * DHID * sizeof(float));
    float* h2      = (float*)carve((size_t)B_ * N_ * DOUT2 * sizeof(float));

    // 1. adjacency -> neighbor lists
    k_build_csr<<<N_, 256, 0, stream>>>(graph, nbr_cnt, nbr_idx);

    // 2. layer 1 linear
    k_linear<DIN1, DHID><<<(B_ * N_) / 32, 256, 0, stream>>>(flow_x, W1, h1);

    // 3. layer 1 attention + bias + relu (one query per wave)
    k_attn<DHID, true><<<N_ * B_ / 4, 256, 0, stream>>>(h1, nbr_cnt, nbr_idx, b1, x2);

    // 4. layer 2 linear
    k_linear<DHID, DOUT2><<<(B_ * N_) / 32, 256, 0, stream>>>(x2, W2, h2);

    // 5. layer 2 attention + bias -> d_out  ([B,N,1,64] is flat-identical)
    k_attn<DOUT2, false><<<N_ * B_ / 4, 256, 0, stream>>>(h2, nbr_cnt, nbr_idx, b2, out);
}

// Round 8
// 270.084 us; speedup vs baseline: 1.1008x; 1.1008x over previous
//
#include <hip/hip_runtime.h>
#include <hip/hip_bf16.h>
#include <cmath>

// Problem constants
#define B_   8
#define N_   4096
#define DIN1 64
#define DHID 128
#define DOUT2 64
#define MAXDEG 256

// ---------------------------------------------------------------------------
// Kernel 1: adjacency -> fixed-stride neighbor lists (float4 scan).
// ---------------------------------------------------------------------------
__global__ __launch_bounds__(256) void k_build_csr(
    const float* __restrict__ graph, int* __restrict__ cnt, int* __restrict__ idx)
{
    const int n = blockIdx.x;
    __shared__ int lcnt;
    if (threadIdx.x == 0) lcnt = 0;
    __syncthreads();
    const float4* row4 = (const float4*)(graph + (size_t)n * N_);
    int* myidx = idx + (size_t)n * MAXDEG;
    for (int m4 = threadIdx.x; m4 < N_ / 4; m4 += 256) {
        float4 g = row4[m4];
        if (g.x != 0.0f) { int p = atomicAdd(&lcnt, 1); if (p < MAXDEG) myidx[p] = 4 * m4; }
        if (g.y != 0.0f) { int p = atomicAdd(&lcnt, 1); if (p < MAXDEG) myidx[p] = 4 * m4 + 1; }
        if (g.z != 0.0f) { int p = atomicAdd(&lcnt, 1); if (p < MAXDEG) myidx[p] = 4 * m4 + 2; }
        if (g.w != 0.0f) { int p = atomicAdd(&lcnt, 1); if (p < MAXDEG) myidx[p] = 4 * m4 + 3; }
    }
    __syncthreads();
    if (threadIdx.x == 0) cnt[n] = (lcnt < MAXDEG) ? lcnt : MAXDEG;
}

// ---------------------------------------------------------------------------
// Kernel 2: register-tiled linear. out[r,k] = sum_d x[r,d]*W[k,d].
// ---------------------------------------------------------------------------
template <int DIN, int DOUT>
__global__ __launch_bounds__(256) void k_linear(
    const float* __restrict__ x, const float* __restrict__ W,
    float* __restrict__ out)
{
    constexpr int CG = DOUT / 4;
    constexpr int RG = 256 / CG;
    constexpr int TR = 32 / RG;

    __shared__ float sWt[DIN][DOUT + 4];

    const int t = threadIdx.x;
    const float4* W4 = (const float4*)W;
    for (int i = t; i < DOUT * (DIN / 4); i += 256) {
        int kk = i / (DIN / 4);
        int d4 = i % (DIN / 4);
        float4 w = W4[i];
        sWt[4 * d4 + 0][kk] = w.x;
        sWt[4 * d4 + 1][kk] = w.y;
        sWt[4 * d4 + 2][kk] = w.z;
        sWt[4 * d4 + 3][kk] = w.w;
    }
    __syncthreads();

    const int rg = t / CG;
    const int c  = t % CG;
    const int base = blockIdx.x * 32;
    const float4* x4 = (const float4*)x;

    float acc[TR][4];
#pragma unroll
    for (int i = 0; i < TR; ++i)
#pragma unroll
        for (int j = 0; j < 4; ++j) acc[i][j] = 0.0f;

    for (int d4 = 0; d4 < DIN / 4; ++d4) {
        float4 xf[TR];
#pragma unroll
        for (int i = 0; i < TR; ++i)
            xf[i] = x4[(size_t)(base + rg * TR + i) * (DIN / 4) + d4];
        float4 wf[4];
#pragma unroll
        for (int dd = 0; dd < 4; ++dd)
            wf[dd] = *(const float4*)&sWt[4 * d4 + dd][4 * c];
#pragma unroll
        for (int i = 0; i < TR; ++i) {
            acc[i][0] += xf[i].x * wf[0].x + xf[i].y * wf[1].x + xf[i].z * wf[2].x + xf[i].w * wf[3].x;
            acc[i][1] += xf[i].x * wf[0].y + xf[i].y * wf[1].y + xf[i].z * wf[2].y + xf[i].w * wf[3].y;
            acc[i][2] += xf[i].x * wf[0].z + xf[i].y * wf[1].z + xf[i].z * wf[2].z + xf[i].w * wf[3].z;
            acc[i][3] += xf[i].x * wf[0].w + xf[i].y * wf[1].w + xf[i].z * wf[2].w + xf[i].w * wf[3].w;
        }
    }

#pragma unroll
    for (int i = 0; i < TR; ++i) {
        float4 o = {acc[i][0], acc[i][1], acc[i][2], acc[i][3]};
        ((float4*)out)[(size_t)(base + rg * TR + i) * CG + c] = o;
    }
}

// ---------------------------------------------------------------------------
// Kernel 3: online-softmax sparse masked attention. One query per wave; 4
// groups of 16 lanes stream disjoint neighbor subsets (each row read from L2
// once). Running max initialized to the SELF-SCORE ||q||^2 (self-loop always
// present, dominates cross-scores) -> the divergent rescale path is cold;
// hot path = dot + exp + 1 FMA/elem. 32-bit pre-scaled byte offsets in LDS
// (no 64-bit address mul chains). Neighbor list padded with 12 zero-offsets
// -> guard-free depth-2 prefetch, triple-buffer, no register copies.
// Exact torch masked_fill(s==0) semantics; all-masked uniform-softmax
// fallback = in-kernel rare path (dead in practice via self-loop).
// ---------------------------------------------------------------------------
template <int D, bool RELU>
__global__ __launch_bounds__(256) void k_attn(
    const float* __restrict__ h, const int* __restrict__ cnt,
    const int* __restrict__ idx, const float* __restrict__ bias,
    float* __restrict__ out)
{
    constexpr int V  = D / 4;    // float4s per row (32 or 16)
    constexpr int NF = V / 16;   // float4s per lane (2 or 1)
    constexpr int RB = D * 4;    // row bytes (512 or 256)

    const int bid  = blockIdx.x;
    const int b    = bid & 7;                    // batch -> XCD pinning
    const int wave = threadIdx.x >> 6;
    const int lane = threadIdx.x & 63;
    const int n    = (bid >> 3) * 4 + wave;      // one query per wave
    const int grp  = lane >> 4;                  // 4 neighbor streams
    const int gl   = lane & 15;

    __shared__ int s_off[4][MAXDEG + 12];        // wave-private byte offsets

    const int k = cnt[n];
    const int* __restrict__ myidx = idx + (size_t)n * MAXDEG;
    for (int j = lane; j < k; j += 64) s_off[wave][j] = myidx[j] * RB;
    if (lane < 12) s_off[wave][k + lane] = 0;    // pad: safe prefetch targets

    const char* __restrict__ hb = (const char*)h + (size_t)b * N_ * RB;
    const int lb = gl * 16;                       // lane's byte slot in row

    float4 qf[NF];
#pragma unroll
    for (int i = 0; i < NF; ++i)
        qf[i] = *(const float4*)(hb + (size_t)n * RB + lb + 256 * i);

    // self-score init: m = ||q||^2 (same op order as the loop dot)
    float m;
    {
        float p = 0.0f;
#pragma unroll
        for (int i = 0; i < NF; ++i)
            p += qf[i].x * qf[i].x + qf[i].y * qf[i].y
               + qf[i].z * qf[i].z + qf[i].w * qf[i].w;
        p += __shfl_xor(p, 8, 64);
        p += __shfl_xor(p, 4, 64);
        p += __shfl_xor(p, 2, 64);
        p += __shfl_xor(p, 1, 64);
        m = (p != 0.0f) ? p : -INFINITY;
    }
    float s = 0.0f;
    float4 acc[NF];
#pragma unroll
    for (int i = 0; i < NF; ++i) acc[i] = {0.0f, 0.0f, 0.0f, 0.0f};

    auto loadrow = [&](float4 (&r)[NF], int j) {
        const char* hm = hb + s_off[wave][j];
#pragma unroll
        for (int i = 0; i < NF; ++i) r[i] = *(const float4*)(hm + lb + 256 * i);
    };
    auto process = [&](const float4 (&cur)[NF]) {
        float p = 0.0f;
#pragma unroll
        for (int i = 0; i < NF; ++i)
            p += qf[i].x * cur[i].x + qf[i].y * cur[i].y
               + qf[i].z * cur[i].z + qf[i].w * cur[i].w;
        p += __shfl_xor(p, 8, 64);
        p += __shfl_xor(p, 4, 64);
        p += __shfl_xor(p, 2, 64);
        p += __shfl_xor(p, 1, 64);
        if (p != 0.0f) {                          // dot==0 => masked (torch)
            if (__builtin_expect(p > m, 0)) {     // cold: beats self-score
                const float f = __expf(m - p);
                s = s * f + 1.0f;
#pragma unroll
                for (int i = 0; i < NF; ++i) {
                    acc[i].x = acc[i].x * f + cur[i].x;
                    acc[i].y = acc[i].y * f + cur[i].y;
                    acc[i].z = acc[i].z * f + cur[i].z;
                    acc[i].w = acc[i].w * f + cur[i].w;
                }
                m = p;
            } else {                              // hot: 1 FMA per element
                const float e = __expf(p - m);
                s += e;
#pragma unroll
                for (int i = 0; i < NF; ++i) {
                    acc[i].x += e * cur[i].x;
                    acc[i].y += e * cur[i].y;
                    acc[i].z += e * cur[i].z;
                    acc[i].w += e * cur[i].w;
                }
            }
        }
    };

    // depth-2 guard-free pipeline (pad makes overshoot loads safe)
    {
        float4 r0[NF], r1[NF], r2[NF];
        loadrow(r0, grp);
        loadrow(r1, grp + 4);
        int j = grp;
        while (j < k) {
            loadrow(r2, j + 8);
            process(r0);
            j += 4; if (j >= k) break;
            loadrow(r0, j + 8);
            process(r1);
            j += 4; if (j >= k) break;
            loadrow(r1, j + 8);
            process(r2);
            j += 4;
        }
    }

    // merge the 4 group states (xor 16, 32); all 64 lanes converge
#pragma unroll
    for (int mask = 16; mask <= 32; mask <<= 1) {
        const float m2 = __shfl_xor(m, mask, 64);
        const float s2 = __shfl_xor(s, mask, 64);
        float4 a2[NF];
#pragma unroll
        for (int i = 0; i < NF; ++i) {
            a2[i].x = __shfl_xor(acc[i].x, mask, 64);
            a2[i].y = __shfl_xor(acc[i].y, mask, 64);
            a2[i].z = __shfl_xor(acc[i].z, mask, 64);
            a2[i].w = __shfl_xor(acc[i].w, mask, 64);
        }
        const float mm = fmaxf(m, m2);
        const float f1 = (m  == mm) ? 1.0f : __expf(m  - mm);  // -inf guard
        const float f2 = (m2 == mm) ? 1.0f : __expf(m2 - mm);
        s = s * f1 + s2 * f2;
#pragma unroll
        for (int i = 0; i < NF; ++i) {
            acc[i].x = acc[i].x * f1 + a2[i].x * f2;
            acc[i].y = acc[i].y * f1 + a2[i].y * f2;
            acc[i].z = acc[i].z * f1 + a2[i].z * f2;
            acc[i].w = acc[i].w * f1 + a2[i].w * f2;
        }
        m = mm;
    }

    if (s > 0.0f) {
        // normal epilogue: group 0 (lanes 0..15) writes the row
        if (grp == 0) {
            const float4* bias4 = (const float4*)bias;
            const float inv = 1.0f / s;
#pragma unroll
            for (int i = 0; i < NF; ++i) {
                const float4 bi = bias4[gl + 16 * i];
                float4 o;
                o.x = acc[i].x * inv + bi.x;
                o.y = acc[i].y * inv + bi.y;
                o.z = acc[i].z * inv + bi.z;
                o.w = acc[i].w * inv + bi.w;
                if (RELU) {
                    o.x = fmaxf(o.x, 0.0f); o.y = fmaxf(o.y, 0.0f);
                    o.z = fmaxf(o.z, 0.0f); o.w = fmaxf(o.w, 0.0f);
                }
                ((float4*)out)[((size_t)b * N_ + n) * V + gl + 16 * i] = o;
            }
        }
    } else {
        // RARE path (all scores masked): uniform softmax over all N rows ->
        // column mean of h[b]. Never taken unless the whole q row is zero.
        const float4* hb4 = (const float4*)hb;
        constexpr int RS = 64 / V;
        const int sl = lane % V;
        const int rs = lane / V;
        float4 a = {0.0f, 0.0f, 0.0f, 0.0f};
        for (int row = rs; row < N_; row += RS) {
            float4 v = hb4[(size_t)row * V + sl];
            a.x += v.x; a.y += v.y; a.z += v.z; a.w += v.w;
        }
#pragma unroll
        for (int mask = V; mask < 64; mask <<= 1) {
            a.x += __shfl_xor(a.x, mask, 64);
            a.y += __shfl_xor(a.y, mask, 64);
            a.z += __shfl_xor(a.z, mask, 64);
            a.w += __shfl_xor(a.w, mask, 64);
        }
        if (lane < V) {
            constexpr float invN = 1.0f / (float)N_;
            const float4 bi = ((const float4*)bias)[sl];
            float4 o;
            o.x = a.x * invN + bi.x;
            o.y = a.y * invN + bi.y;
            o.z = a.z * invN + bi.z;
            o.w = a.w * invN + bi.w;
            if (RELU) {
                o.x = fmaxf(o.x, 0.0f); o.y = fmaxf(o.y, 0.0f);
                o.z = fmaxf(o.z, 0.0f); o.w = fmaxf(o.w, 0.0f);
            }
            ((float4*)out)[((size_t)b * N_ + n) * V + sl] = o;
        }
    }
}

// ---------------------------------------------------------------------------
// Launch
// ---------------------------------------------------------------------------
extern "C" void kernel_launch(void* const* d_in, const int* in_sizes, int n_in,
                              void* d_out, int out_size, void* d_ws, size_t ws_size,
                              hipStream_t stream) {
    (void)in_sizes; (void)n_in; (void)out_size; (void)ws_size;

    const float* flow_x = (const float*)d_in[0];
    const float* graph  = (const float*)d_in[1];
    const float* W1     = (const float*)d_in[2];
    const float* b1     = (const float*)d_in[3];
    const float* W2     = (const float*)d_in[4];
    const float* b2     = (const float*)d_in[5];
    float* out = (float*)d_out;

    char* p = (char*)d_ws;
    auto carve = [&](size_t bytes) -> void* {
        void* r = (void*)p;
        p += (bytes + 255) & ~(size_t)255;
        return r;
    };
    int*   nbr_cnt = (int*)carve((size_t)N_ * sizeof(int));
    int*   nbr_idx = (int*)carve((size_t)N_ * MAXDEG * sizeof(int));
    float* h1      = (float*)carve((size_t)B_ * N_ * DHID * sizeof(float));
    float* x2      = (float*)carve((size_t)B_ * N_ * DHID * sizeof(float));
    float* h2      = (float*)carve((size_t)B_ * N_ * DOUT2 * sizeof(float));

    // 1. adjacency -> neighbor lists
    k_build_csr<<<N_, 256, 0, stream>>>(graph, nbr_cnt, nbr_idx);

    // 2. layer 1 linear
    k_linear<DIN1, DHID><<<(B_ * N_) / 32, 256, 0, stream>>>(flow_x, W1, h1);

    // 3. layer 1 attention + bias + relu (one query per wave)
    k_attn<DHID, true><<<N_ * B_ / 4, 256, 0, stream>>>(h1, nbr_cnt, nbr_idx, b1, x2);

    // 4. layer 2 linear
    k_linear<DHID, DOUT2><<<(B_ * N_) / 32, 256, 0, stream>>>(x2, W2, h2);

    // 5. layer 2 attention + bias -> d_out  ([B,N,1,64] is flat-identical)
    k_attn<DOUT2, false><<<N_ * B_ / 4, 256, 0, stream>>>(h2, nbr_cnt, nbr_idx, b2, out);
}

// Round 9
// 267.698 us; speedup vs baseline: 1.1106x; 1.0089x over previous
//
#include <hip/hip_runtime.h>
#include <hip/hip_bf16.h>
#include <cmath>

// Problem constants
#define B_   8
#define N_   4096
#define DIN1 64
#define DHID 128
#define DOUT2 64
#define MAXDEG 256

// ---------------------------------------------------------------------------
// Kernel 1: adjacency -> fixed-stride neighbor lists (float4 scan).
// ---------------------------------------------------------------------------
__global__ __launch_bounds__(256) void k_build_csr(
    const float* __restrict__ graph, int* __restrict__ cnt, int* __restrict__ idx)
{
    const int n = blockIdx.x;
    __shared__ int lcnt;
    if (threadIdx.x == 0) lcnt = 0;
    __syncthreads();
    const float4* row4 = (const float4*)(graph + (size_t)n * N_);
    int* myidx = idx + (size_t)n * MAXDEG;
    for (int m4 = threadIdx.x; m4 < N_ / 4; m4 += 256) {
        float4 g = row4[m4];
        if (g.x != 0.0f) { int p = atomicAdd(&lcnt, 1); if (p < MAXDEG) myidx[p] = 4 * m4; }
        if (g.y != 0.0f) { int p = atomicAdd(&lcnt, 1); if (p < MAXDEG) myidx[p] = 4 * m4 + 1; }
        if (g.z != 0.0f) { int p = atomicAdd(&lcnt, 1); if (p < MAXDEG) myidx[p] = 4 * m4 + 2; }
        if (g.w != 0.0f) { int p = atomicAdd(&lcnt, 1); if (p < MAXDEG) myidx[p] = 4 * m4 + 3; }
    }
    __syncthreads();
    if (threadIdx.x == 0) cnt[n] = (lcnt < MAXDEG) ? lcnt : MAXDEG;
}

// ---------------------------------------------------------------------------
// Kernel 2: register-tiled linear. out[r,k] = sum_d x[r,d]*W[k,d].
// ---------------------------------------------------------------------------
template <int DIN, int DOUT>
__global__ __launch_bounds__(256) void k_linear(
    const float* __restrict__ x, const float* __restrict__ W,
    float* __restrict__ out)
{
    constexpr int CG = DOUT / 4;
    constexpr int RG = 256 / CG;
    constexpr int TR = 32 / RG;

    __shared__ float sWt[DIN][DOUT + 4];

    const int t = threadIdx.x;
    const float4* W4 = (const float4*)W;
    for (int i = t; i < DOUT * (DIN / 4); i += 256) {
        int kk = i / (DIN / 4);
        int d4 = i % (DIN / 4);
        float4 w = W4[i];
        sWt[4 * d4 + 0][kk] = w.x;
        sWt[4 * d4 + 1][kk] = w.y;
        sWt[4 * d4 + 2][kk] = w.z;
        sWt[4 * d4 + 3][kk] = w.w;
    }
    __syncthreads();

    const int rg = t / CG;
    const int c  = t % CG;
    const int base = blockIdx.x * 32;
    const float4* x4 = (const float4*)x;

    float acc[TR][4];
#pragma unroll
    for (int i = 0; i < TR; ++i)
#pragma unroll
        for (int j = 0; j < 4; ++j) acc[i][j] = 0.0f;

    for (int d4 = 0; d4 < DIN / 4; ++d4) {
        float4 xf[TR];
#pragma unroll
        for (int i = 0; i < TR; ++i)
            xf[i] = x4[(size_t)(base + rg * TR + i) * (DIN / 4) + d4];
        float4 wf[4];
#pragma unroll
        for (int dd = 0; dd < 4; ++dd)
            wf[dd] = *(const float4*)&sWt[4 * d4 + dd][4 * c];
#pragma unroll
        for (int i = 0; i < TR; ++i) {
            acc[i][0] += xf[i].x * wf[0].x + xf[i].y * wf[1].x + xf[i].z * wf[2].x + xf[i].w * wf[3].x;
            acc[i][1] += xf[i].x * wf[0].y + xf[i].y * wf[1].y + xf[i].z * wf[2].y + xf[i].w * wf[3].y;
            acc[i][2] += xf[i].x * wf[0].z + xf[i].y * wf[1].z + xf[i].z * wf[2].z + xf[i].w * wf[3].z;
            acc[i][3] += xf[i].x * wf[0].w + xf[i].y * wf[1].w + xf[i].z * wf[2].w + xf[i].w * wf[3].w;
        }
    }

#pragma unroll
    for (int i = 0; i < TR; ++i) {
        float4 o = {acc[i][0], acc[i][1], acc[i][2], acc[i][3]};
        ((float4*)out)[(size_t)(base + rg * TR + i) * CG + c] = o;
    }
}

// ---------------------------------------------------------------------------
// Kernel 3: online-softmax sparse masked attention with THRESHOLD SKIP.
// One query per wave; 4 groups of 16 lanes stream disjoint neighbor subsets
// (each row read from L2 once). m initialized to the self-score ||q||^2.
// Hot loop: load + dot + 4 shuffles + ONE wave-uniform compare -- exp and
// the accumulate are only executed when some lane has p > m-100 (self term
// + near-max terms, ~1-2 iterations/query). Exact: terms with p <= m-100
// contribute < e^-100 ~ 1e-44 < 1 ulp of s; the taken path is the full
// two-sided flash update, correct for arbitrary data. 32-bit pre-scaled
// byte offsets in LDS; 12 zero-offset pads -> guard-free depth-2 prefetch.
// Exact torch masked_fill(s==0) semantics; all-masked uniform-softmax
// fallback = in-kernel rare path (dead in practice via self-loop).
// ---------------------------------------------------------------------------
template <int D, bool RELU>
__global__ __launch_bounds__(256) void k_attn(
    const float* __restrict__ h, const int* __restrict__ cnt,
    const int* __restrict__ idx, const float* __restrict__ bias,
    float* __restrict__ out)
{
    constexpr int V  = D / 4;    // float4s per row (32 or 16)
    constexpr int NF = V / 16;   // float4s per lane (2 or 1)
    constexpr int RB = D * 4;    // row bytes (512 or 256)

    const int bid  = blockIdx.x;
    const int b    = bid & 7;                    // batch -> XCD pinning
    const int wave = threadIdx.x >> 6;
    const int lane = threadIdx.x & 63;
    const int n    = (bid >> 3) * 4 + wave;      // one query per wave
    const int grp  = lane >> 4;                  // 4 neighbor streams
    const int gl   = lane & 15;

    __shared__ int s_off[4][MAXDEG + 12];        // wave-private byte offsets

    const int k = cnt[n];
    const int* __restrict__ myidx = idx + (size_t)n * MAXDEG;
    for (int j = lane; j < k; j += 64) s_off[wave][j] = myidx[j] * RB;
    if (lane < 12) s_off[wave][k + lane] = 0;    // pad: safe prefetch targets

    const char* __restrict__ hb = (const char*)h + (size_t)b * N_ * RB;
    const int lb = gl * 16;                       // lane's byte slot in row

    float4 qf[NF];
#pragma unroll
    for (int i = 0; i < NF; ++i)
        qf[i] = *(const float4*)(hb + (size_t)n * RB + lb + 256 * i);

    // self-score init: m = ||q||^2 (same op structure as the loop dot)
    float m;
    {
        float p = 0.0f;
#pragma unroll
        for (int i = 0; i < NF; ++i)
            p += qf[i].x * qf[i].x + qf[i].y * qf[i].y
               + qf[i].z * qf[i].z + qf[i].w * qf[i].w;
        p += __shfl_xor(p, 8, 64);
        p += __shfl_xor(p, 4, 64);
        p += __shfl_xor(p, 2, 64);
        p += __shfl_xor(p, 1, 64);
        m = (p != 0.0f) ? p : -INFINITY;
    }
    float mt = m - 100.0f;                       // skip threshold
    float s = 0.0f;
    float4 acc[NF];
#pragma unroll
    for (int i = 0; i < NF; ++i) acc[i] = {0.0f, 0.0f, 0.0f, 0.0f};

    auto loadrow = [&](float4 (&r)[NF], int j) {
        const char* hm = hb + s_off[wave][j];
#pragma unroll
        for (int i = 0; i < NF; ++i) r[i] = *(const float4*)(hm + lb + 256 * i);
    };
    auto process = [&](const float4 (&cur)[NF]) {
        float p = 0.0f;
#pragma unroll
        for (int i = 0; i < NF; ++i)
            p += qf[i].x * cur[i].x + qf[i].y * cur[i].y
               + qf[i].z * cur[i].z + qf[i].w * cur[i].w;
        p += __shfl_xor(p, 8, 64);
        p += __shfl_xor(p, 4, 64);
        p += __shfl_xor(p, 2, 64);
        p += __shfl_xor(p, 1, 64);
        // terms with p <= m-100 contribute < e^-100 (sub-ulp of s): skip.
        if (__builtin_expect(__any(p > mt), 0)) {
            const bool valid = (p != 0.0f);       // dot==0 => masked (torch)
            const float pm   = valid ? p : m;
            const float newm = fmaxf(m, pm);
            const float f = (m == newm) ? 1.0f : __expf(m - newm);
            const float e = valid ? __expf(p - newm) : 0.0f;
            s = s * f + e;
#pragma unroll
            for (int i = 0; i < NF; ++i) {
                acc[i].x = acc[i].x * f + e * cur[i].x;
                acc[i].y = acc[i].y * f + e * cur[i].y;
                acc[i].z = acc[i].z * f + e * cur[i].z;
                acc[i].w = acc[i].w * f + e * cur[i].w;
            }
            m = newm;
            mt = m - 100.0f;
        }
    };

    // depth-2 guard-free pipeline (pad makes overshoot loads safe)
    {
        float4 r0[NF], r1[NF], r2[NF];
        loadrow(r0, grp);
        loadrow(r1, grp + 4);
        int j = grp;
        while (j < k) {
            loadrow(r2, j + 8);
            process(r0);
            j += 4; if (j >= k) break;
            loadrow(r0, j + 8);
            process(r1);
            j += 4; if (j >= k) break;
            loadrow(r1, j + 8);
            process(r2);
            j += 4;
        }
    }

    // merge the 4 group states (xor 16, 32); all 64 lanes converge
#pragma unroll
    for (int mask = 16; mask <= 32; mask <<= 1) {
        const float m2 = __shfl_xor(m, mask, 64);
        const float s2 = __shfl_xor(s, mask, 64);
        float4 a2[NF];
#pragma unroll
        for (int i = 0; i < NF; ++i) {
            a2[i].x = __shfl_xor(acc[i].x, mask, 64);
            a2[i].y = __shfl_xor(acc[i].y, mask, 64);
            a2[i].z = __shfl_xor(acc[i].z, mask, 64);
            a2[i].w = __shfl_xor(acc[i].w, mask, 64);
        }
        const float mm = fmaxf(m, m2);
        const float f1 = (m  == mm) ? 1.0f : __expf(m  - mm);  // -inf guard
        const float f2 = (m2 == mm) ? 1.0f : __expf(m2 - mm);
        s = s * f1 + s2 * f2;
#pragma unroll
        for (int i = 0; i < NF; ++i) {
            acc[i].x = acc[i].x * f1 + a2[i].x * f2;
            acc[i].y = acc[i].y * f1 + a2[i].y * f2;
            acc[i].z = acc[i].z * f1 + a2[i].z * f2;
            acc[i].w = acc[i].w * f1 + a2[i].w * f2;
        }
        m = mm;
    }

    if (s > 0.0f) {
        // normal epilogue: group 0 (lanes 0..15) writes the row
        if (grp == 0) {
            const float4* bias4 = (const float4*)bias;
            const float inv = 1.0f / s;
#pragma unroll
            for (int i = 0; i < NF; ++i) {
                const float4 bi = bias4[gl + 16 * i];
                float4 o;
                o.x = acc[i].x * inv + bi.x;
                o.y = acc[i].y * inv + bi.y;
                o.z = acc[i].z * inv + bi.z;
                o.w = acc[i].w * inv + bi.w;
                if (RELU) {
                    o.x = fmaxf(o.x, 0.0f); o.y = fmaxf(o.y, 0.0f);
                    o.z = fmaxf(o.z, 0.0f); o.w = fmaxf(o.w, 0.0f);
                }
                ((float4*)out)[((size_t)b * N_ + n) * V + gl + 16 * i] = o;
            }
        }
    } else {
        // RARE path (all scores masked): uniform softmax over all N rows ->
        // column mean of h[b]. Never taken unless the whole q row is zero.
        const float4* hb4 = (const float4*)hb;
        constexpr int RS = 64 / V;
        const int sl = lane % V;
        const int rs = lane / V;
        float4 a = {0.0f, 0.0f, 0.0f, 0.0f};
        for (int row = rs; row < N_; row += RS) {
            float4 v = hb4[(size_t)row * V + sl];
            a.x += v.x; a.y += v.y; a.z += v.z; a.w += v.w;
        }
#pragma unroll
        for (int mask = V; mask < 64; mask <<= 1) {
            a.x += __shfl_xor(a.x, mask, 64);
            a.y += __shfl_xor(a.y, mask, 64);
            a.z += __shfl_xor(a.z, mask, 64);
            a.w += __shfl_xor(a.w, mask, 64);
        }
        if (lane < V) {
            constexpr float invN = 1.0f / (float)N_;
            const float4 bi = ((const float4*)bias)[sl];
            float4 o;
            o.x = a.x * invN + bi.x;
            o.y = a.y * invN + bi.y;
            o.z = a.z * invN + bi.z;
            o.w = a.w * invN + bi.w;
            if (RELU) {
                o.x = fmaxf(o.x, 0.0f); o.y = fmaxf(o.y, 0.0f);
                o.z = fmaxf(o.z, 0.0f); o.w = fmaxf(o.w, 0.0f);
            }
            ((float4*)out)[((size_t)b * N_ + n) * V + sl] = o;
        }
    }
}

// ---------------------------------------------------------------------------
// Launch
// ---------------------------------------------------------------------------
extern "C" void kernel_launch(void* const* d_in, const int* in_sizes, int n_in,
                              void* d_out, int out_size, void* d_ws, size_t ws_size,
                              hipStream_t stream) {
    (void)in_sizes; (void)n_in; (void)out_size; (void)ws_size;

    const float* flow_x = (const float*)d_in[0];
    const float* graph  = (const float*)d_in[1];
    const float* W1     = (const float*)d_in[2];
    const float* b1     = (const float*)d_in[3];
    const float* W2     = (const float*)d_in[4];
    const float* b2     = (const float*)d_in[5];
    float* out = (float*)d_out;

    char* p = (char*)d_ws;
    auto carve = [&](size_t bytes) -> void* {
        void* r = (void*)p;
        p += (bytes + 255) & ~(size_t)255;
        return r;
    };
    int*   nbr_cnt = (int*)carve((size_t)N_ * sizeof(int));
    int*   nbr_idx = (int*)carve((size_t)N_ * MAXDEG * sizeof(int));
    float* h1      = (float*)carve((size_t)B_ * N_ * DHID * sizeof(float));
    float* x2      = (float*)carve((size_t)B_ * N_ * DHID * sizeof(float));
    float* h2      = (float*)carve((size_t)B_ * N_ * DOUT2 * sizeof(float));

    // 1. adjacency -> neighbor lists
    k_build_csr<<<N_, 256, 0, stream>>>(graph, nbr_cnt, nbr_idx);

    // 2. layer 1 linear
    k_linear<DIN1, DHID><<<(B_ * N_) / 32, 256, 0, stream>>>(flow_x, W1, h1);

    // 3. layer 1 attention + bias + relu (one query per wave)
    k_attn<DHID, true><<<N_ * B_ / 4, 256, 0, stream>>>(h1, nbr_cnt, nbr_idx, b1, x2);

    // 4. layer 2 linear
    k_linear<DHID, DOUT2><<<(B_ * N_) / 32, 256, 0, stream>>>(x2, W2, h2);

    // 5. layer 2 attention + bias -> d_out  ([B,N,1,64] is flat-identical)
    k_attn<DOUT2, false><<<N_ * B_ / 4, 256, 0, stream>>>(h2, nbr_cnt, nbr_idx, b2, out);
}